// Round 6
// baseline (147.194 us; speedup 1.0000x reference)
//
#include <hip/hip_runtime.h>
#include <hip/hip_bf16.h>

// TokenEncoder: B=8 L=2048 D=512 DM=1024 S=32 M=4 P=4096
// out = [tokens (8,2049,1024) f32][attn_keep (8,2049) as f32]

#define NB   8
#define NL   2048
#define ND   512
#define NDM  1024
#define NS   32
#define NTOK (NB * NL)          // 16384
#define LP1  (NL + 1)           // 2049
#define MAXTILES 96             // sum ceil(cnt_e/256) <= 58+32
#define EXP_CAP 1024
#define EMB_ELEMS (NTOK * ND)   // 8388608
#define W_ELEMS (NS * NDM * ND) // 16777216

static __device__ __forceinline__ size_t attn_off() { return (size_t)NB * LP1 * NDM; }

typedef __attribute__((ext_vector_type(8))) short bf16x8;
typedef __attribute__((ext_vector_type(4))) float f32x4;

__device__ __forceinline__ unsigned short f2bf(float f) {
    unsigned int x = __float_as_uint(f);
    x += 0x7fffu + ((x >> 16) & 1u);   // RNE (inputs finite)
    return (unsigned short)(x >> 16);
}

__device__ __forceinline__ bf16x8 cvt8(float4 a, float4 b) {
    bf16x8 r;
    r[0] = (short)f2bf(a.x); r[1] = (short)f2bf(a.y);
    r[2] = (short)f2bf(a.z); r[3] = (short)f2bf(a.w);
    r[4] = (short)f2bf(b.x); r[5] = (short)f2bf(b.y);
    r[6] = (short)f2bf(b.z); r[7] = (short)f2bf(b.w);
    return r;
}

__device__ __forceinline__ float4 ld4(const float* p) { return *(const float4*)p; }
__device__ __forceinline__ float4 add4(float4 a, float4 b) {
    return make_float4(a.x + b.x, a.y + b.y, a.z + b.z, a.w + b.w);
}

__device__ __forceinline__ void gl_lds16(const void* g, void* l) {
    __builtin_amdgcn_global_load_lds((const __attribute__((address_space(1))) void*)g,
                                     (__attribute__((address_space(3))) void*)l, 16, 0, 0);
}

// ---- kernel 1: bucket tokens per expert (packed id|pos|mr), rest-list, attn ----
__global__ void k_bucket(const int* __restrict__ sid, const int* __restrict__ mask,
                         const int* __restrict__ pos, const int* __restrict__ mod,
                         const int* __restrict__ role,
                         int* __restrict__ cnt, int* __restrict__ restCnt,
                         int* __restrict__ tokList, int* __restrict__ restList,
                         float* __restrict__ out) {
    int t = blockIdx.x * 256 + threadIdx.x;
    if (t >= NTOK) return;
    int s = sid[t];
    bool keep = mask[t] != 0;
    int b = t >> 11, l = t & (NL - 1);
    out[attn_off() + (size_t)b * LP1 + l + 1] = keep ? 1.0f : 0.0f;
    if (t < NB) out[attn_off() + (size_t)t * LP1] = 1.0f;   // CLS keep
    int mr = mod[t] * 3 + role[t];
    int packed = t | (pos[t] << 14) | (mr << 27);           // 14+13+4 bits
    if (keep) {
        int idx = atomicAdd(&cnt[s], 1);
        if (idx < EXP_CAP) tokList[s * EXP_CAP + idx] = packed;
    } else {
        int ridx = atomicAdd(restCnt, 1);
        restList[ridx] = packed;
    }
}

// ---- kernel 2: tile descriptors (BM=256) + mod×role table ----
__global__ void k_tiles(const int* __restrict__ cnt, int* __restrict__ meta,
                        int4* __restrict__ tiles,
                        const float* __restrict__ me, const float* __restrict__ re,
                        float* __restrict__ mrT) {
    if (threadIdx.x == 0) {
        int idx = 0;
        for (int e = 0; e < NS; ++e) {
            int c = min(cnt[e], EXP_CAP);
            for (int r = 0; r < c; r += 256)
                tiles[idx++] = make_int4(e, r, min(256, c - r), 0);
        }
        meta[0] = idx;
    }
    for (int i = threadIdx.x; i < 12 * (NDM / 4); i += 256) {
        int mr = i / (NDM / 4); int o = (i % (NDM / 4)) * 4;
        int m = mr / 3, ro = mr % 3;
        float4 v = add4(ld4(me + (size_t)m * NDM + o), ld4(re + (size_t)ro * NDM + o));
        *(float4*)&mrT[(size_t)mr * NDM + o] = v;
    }
}

// ---- kernel 3: f32 -> bf16 for emb and W ----
__global__ void k_cvt(const float* __restrict__ emb, const float* __restrict__ W,
                      short* __restrict__ embBf, short* __restrict__ wBf) {
    size_t i = ((size_t)blockIdx.x * 256 + threadIdx.x) * 16;
    const float* src; short* dst;
    if (i < (size_t)EMB_ELEMS) { src = emb + i; dst = embBf + i; }
    else { src = W + (i - EMB_ELEMS); dst = wBf + (i - EMB_ELEMS); }
    float4 a = ld4(src), b = ld4(src + 4), c = ld4(src + 8), d = ld4(src + 12);
    *(bf16x8*)dst       = cvt8(a, b);
    *(bf16x8*)(dst + 8) = cvt8(c, d);
}

// ---- kernel 4: grouped GEMM, 256x256xBK64, 8 waves, dbuf, counted vmcnt ----
__global__ __launch_bounds__(512, 2) void k_gemm(
    const short* __restrict__ embBf, const short* __restrict__ wBf,
    const int* __restrict__ tokList, const int4* __restrict__ tiles,
    const int* __restrict__ meta,
    const float* __restrict__ bp, const float* __restrict__ pe,
    const float* __restrict__ ie, const float* __restrict__ mrT,
    float* __restrict__ out) {
    if (blockIdx.x >= meta[0]) return;
    extern __shared__ short lds[];      // 128KB: A0|A1|B0|B1, 32KB each
    int4 td = tiles[blockIdx.x];
    const int e = td.x, rowBase = td.y, nRows = td.z;
    const int nBase = blockIdx.y * 256;

    const int tid  = threadIdx.x;
    const int lane = tid & 63;
    const int w    = tid >> 6;              // 0..7
    const int wr   = w >> 2, wc = w & 3;    // 2x4 waves; wave out = 128x64
    const int fr   = lane & 15, kg = lane >> 4;
    const int xs   = fr & 7;                // row-parity for read swizzle
    const int c0   = kg ^ xs;               // phys chunk for kk=0 (kk=1: c0^4)

    // staging: per K-tile, thread issues 4 A + 4 B gl_lds; call q covers 8 rows
    // (1KB). LDS linear; swizzle = source-chunk XOR row&7, read-side same XOR.
    const int srow = lane >> 3;                       // 0..7 within 8-row group
    const int schunk = (lane & 7) ^ srow;             // pre-swizzled source chunk
    const short* aSrc[4]; const short* bSrc[4];
#pragma unroll
    for (int q = 0; q < 4; ++q) {
        int r = (w * 4 + q) * 8 + srow;               // 0..255
        int ar = (r < nRows) ? r : 0;
        int tok = tokList[(size_t)e * EXP_CAP + rowBase + ar] & 16383;
        aSrc[q] = embBf + (size_t)tok * ND + schunk * 8;
        bSrc[q] = wBf + ((size_t)e * NDM + nBase + r) * ND + schunk * 8;
    }

    // epilogue col-invariants (issued early; retire before steady-state waits)
    const float* bpE = bp + (size_t)e * NDM;
    const float* ieE = ie + (size_t)e * NDM;
    float eb[4]; int colv[4];
#pragma unroll
    for (int j = 0; j < 4; ++j) {
        colv[j] = nBase + wc * 64 + j * 16 + fr;
        eb[j] = bpE[colv[j]] + ieE[colv[j]];
    }

    f32x4 acc[8][4];
#pragma unroll
    for (int i = 0; i < 8; ++i)
#pragma unroll
        for (int j = 0; j < 4; ++j)
            acc[i][j] = (f32x4){0.f, 0.f, 0.f, 0.f};

#define STAGE(buf, kt) do {                                              \
        const int bo_ = (buf) * 16384;                                   \
        _Pragma("unroll")                                                \
        for (int q = 0; q < 4; ++q) {                                    \
            gl_lds16(aSrc[q] + (kt) * 64, lds + bo_ + (w * 4 + q) * 512);\
            gl_lds16(bSrc[q] + (kt) * 64, lds + 32768 + bo_ + (w * 4 + q) * 512);\
        }                                                                \
    } while (0)

    STAGE(0, 0);
    for (int kt = 0; kt < ND / 64; ++kt) {    // 8 K-tiles
        const int buf = kt & 1;
        if (kt < ND / 64 - 1) {
            STAGE(buf ^ 1, kt + 1);
            asm volatile("s_waitcnt vmcnt(8)" ::: "memory");  // cur 8 landed; next 8 in flight
        } else {
            asm volatile("s_waitcnt vmcnt(0)" ::: "memory");
        }
        __builtin_amdgcn_s_barrier();
        asm volatile("" ::: "memory");
        const short* Aq = lds + buf * 16384;
        const short* Bq = lds + 32768 + buf * 16384;
        bf16x8 bfr[4][2];
#pragma unroll
        for (int j = 0; j < 4; ++j) {
            int base = (wc * 64 + j * 16 + fr) * 64;
            bfr[j][0] = *(const bf16x8*)&Bq[base + c0 * 8];
            bfr[j][1] = *(const bf16x8*)&Bq[base + (c0 ^ 4) * 8];
        }
#pragma unroll
        for (int i = 0; i < 8; ++i) {
            int base = (wr * 128 + i * 16 + fr) * 64;
            bf16x8 a0 = *(const bf16x8*)&Aq[base + c0 * 8];
            bf16x8 a1 = *(const bf16x8*)&Aq[base + (c0 ^ 4) * 8];
#pragma unroll
            for (int j = 0; j < 4; ++j)
                acc[i][j] = __builtin_amdgcn_mfma_f32_16x16x32_bf16(a0, bfr[j][0], acc[i][j], 0, 0, 0);
#pragma unroll
            for (int j = 0; j < 4; ++j)
                acc[i][j] = __builtin_amdgcn_mfma_f32_16x16x32_bf16(a1, bfr[j][1], acc[i][j], 0, 0, 0);
        }
        asm volatile("" ::: "memory");
        __builtin_amdgcn_s_barrier();         // all reads of buf done before restage
    }
#undef STAGE

    // fused epilogue: full value write (no RMW)
#pragma unroll
    for (int i = 0; i < 8; ++i) {
#pragma unroll
        for (int r = 0; r < 4; ++r) {
            int row = wr * 128 + i * 16 + kg * 4 + r;
            if (row < nRows) {
                int pk = tokList[(size_t)e * EXP_CAP + rowBase + row];
                int t = pk & 16383, p = (pk >> 14) & 8191, mr = (pk >> 27) & 15;
                const float* peR = pe + (size_t)p * NDM;
                const float* mrR = mrT + (size_t)mr * NDM;
                size_t orow = ((size_t)(t >> 11) * LP1 + (t & (NL - 1)) + 1) * NDM;
#pragma unroll
                for (int j = 0; j < 4; ++j)
                    out[orow + colv[j]] = acc[i][j][r] + eb[j] + peR[colv[j]] + mrR[colv[j]];
            }
        }
    }
}

// ---- kernel 5: rest rows (padded tokens) + CLS rows, compact grid-stride ----
__global__ void k_rest(const int* __restrict__ sid,
                       const int* __restrict__ restList, const int* __restrict__ meta,
                       const float* __restrict__ cls_c, const float* __restrict__ pos_e,
                       const float* __restrict__ id_e, const float* __restrict__ mrT,
                       float* __restrict__ out) {
    int total = meta[1] + NB;               // rest rows + CLS rows
    int half = threadIdx.x >> 7;            // 2 rows per 256-thread block
    int o = (threadIdx.x & 127) * 8;        // 128 threads x 8 floats = 1024
    for (int rI = blockIdx.x * 2 + half; rI < total; rI += gridDim.x * 2) {
        float4 v0, v1; size_t orow;
        if (rI < NB) {
            const float* ieC = id_e + (size_t)NS * NDM;
            v0 = add4(add4(ld4(cls_c + o), ld4(pos_e + o)), ld4(ieC + o));
            v1 = add4(add4(ld4(cls_c + o + 4), ld4(pos_e + o + 4)), ld4(ieC + o + 4));
            orow = (size_t)rI * LP1 * NDM;
        } else {
            int pk = restList[rI - NB];
            int t = pk & 16383, p = (pk >> 14) & 8191, mr = (pk >> 27) & 15;
            int s = sid[t];
            const float* peR = pos_e + (size_t)p * NDM;
            const float* ieR = id_e + (size_t)s * NDM;
            const float* mrR = mrT + (size_t)mr * NDM;
            v0 = add4(add4(ld4(peR + o), ld4(ieR + o)), ld4(mrR + o));
            v1 = add4(add4(ld4(peR + o + 4), ld4(ieR + o + 4)), ld4(mrR + o + 4));
            orow = ((size_t)(t >> 11) * LP1 + (t & (NL - 1)) + 1) * NDM;
        }
        *(float4*)&out[orow + o] = v0;
        *(float4*)&out[orow + o + 4] = v1;
    }
}

extern "C" void kernel_launch(void* const* d_in, const int* in_sizes, int n_in,
                              void* d_out, int out_size, void* d_ws, size_t ws_size,
                              hipStream_t stream) {
    const float* emb  = (const float*)d_in[0];
    const int* pos    = (const int*)d_in[1];
    const int* sid    = (const int*)d_in[2];
    const int* mod    = (const int*)d_in[3];
    const int* role   = (const int*)d_in[4];
    const int* mask   = (const int*)d_in[5];   // np.bool_ pushed as int32
    const float* Wp   = (const float*)d_in[6];
    const float* bp   = (const float*)d_in[7];
    const float* cls  = (const float*)d_in[8];
    const float* pe   = (const float*)d_in[9];
    const float* ie   = (const float*)d_in[10];
    const float* me   = (const float*)d_in[11];
    const float* re   = (const float*)d_in[12];
    float* out = (float*)d_out;

    int* ws        = (int*)d_ws;
    int* cnt       = ws;                          // [0..31]
    int* meta      = ws + 32;                     // [32]=tileCnt, [33]=restCnt
    int4* tiles    = (int4*)(ws + 128);           // 96 * int4
    int* tokList   = ws + 1024;                   // 32*1024
    int* restList  = ws + 33792;                  // 16384
    float* mrT     = (float*)(ws + 50176);        // 12*1024
    short* embBf   = (short*)((char*)d_ws + 262144);
    short* wBf     = (short*)((char*)d_ws + 262144 + (size_t)EMB_ELEMS * 2);
    // total ws: 262144 + 16.78MB + 33.55MB = 50.6 MB

    static int lds_attr_set = 0;   // host-side idempotent attr (not device state)
    if (!lds_attr_set) {
        hipFuncSetAttribute((const void*)k_gemm,
                            hipFuncAttributeMaxDynamicSharedMemorySize, 131072);
        lds_attr_set = 1;
    }

    hipMemsetAsync(ws, 0, 64 * sizeof(int), stream);
    k_bucket<<<NTOK / 256, 256, 0, stream>>>(sid, mask, pos, mod, role,
                                             cnt, meta + 1, tokList, restList, out);
    k_tiles<<<1, 256, 0, stream>>>(cnt, meta, tiles, me, re, mrT);
    k_cvt<<<(EMB_ELEMS + W_ELEMS) / (256 * 16), 256, 0, stream>>>(emb, Wp, embBf, wBf);

    dim3 gg(MAXTILES, NDM / 256);
    k_gemm<<<gg, 512, 131072, stream>>>(embBf, wBf, tokList, tiles, meta,
                                        bp, pe, ie, mrT, out);
    k_rest<<<512, 256, 0, stream>>>(sid, restList, meta, cls, pe, ie, mrT, out);
}

// Round 8
// 134.504 us; speedup vs baseline: 1.0943x; 1.0943x over previous
//
#include <hip/hip_runtime.h>
#include <hip/hip_bf16.h>

// TokenEncoder: B=8 L=2048 D=512 DM=1024 S=32 M=4 P=4096
// out = [tokens (8,2049,1024) f32][attn_keep (8,2049) as f32]

#define NB   8
#define NL   2048
#define ND   512
#define NDM  1024
#define NS   32
#define NTOK (NB * NL)          // 16384
#define LP1  (NL + 1)           // 2049
#define MAXTILES 160
#define EXP_CAP 1024
#define EMB_ELEMS (NTOK * ND)   // 8388608
#define W_ELEMS (NS * NDM * ND) // 16777216

static __device__ __forceinline__ size_t attn_off() { return (size_t)NB * LP1 * NDM; }

typedef __attribute__((ext_vector_type(8))) short bf16x8;
typedef __attribute__((ext_vector_type(4))) float f32x4;

__device__ __forceinline__ unsigned short f2bf(float f) {
    unsigned int x = __float_as_uint(f);
    x += 0x7fffu + ((x >> 16) & 1u);   // RNE (inputs finite)
    return (unsigned short)(x >> 16);
}

__device__ __forceinline__ bf16x8 cvt8(float4 a, float4 b) {
    bf16x8 r;
    r[0] = (short)f2bf(a.x); r[1] = (short)f2bf(a.y);
    r[2] = (short)f2bf(a.z); r[3] = (short)f2bf(a.w);
    r[4] = (short)f2bf(b.x); r[5] = (short)f2bf(b.y);
    r[6] = (short)f2bf(b.z); r[7] = (short)f2bf(b.w);
    return r;
}

__device__ __forceinline__ float4 ld4(const float* p) { return *(const float4*)p; }
__device__ __forceinline__ float4 add4(float4 a, float4 b) {
    return make_float4(a.x + b.x, a.y + b.y, a.z + b.z, a.w + b.w);
}

// ---- kernel 1: bucket tokens per expert (packed id|pos|mr), rest-list, attn ----
__global__ void k_bucket(const int* __restrict__ sid, const int* __restrict__ mask,
                         const int* __restrict__ pos, const int* __restrict__ mod,
                         const int* __restrict__ role,
                         int* __restrict__ cnt, int* __restrict__ restCnt,
                         int* __restrict__ tokList, int* __restrict__ restList,
                         float* __restrict__ out) {
    int t = blockIdx.x * 256 + threadIdx.x;
    if (t >= NTOK) return;
    int s = sid[t];
    bool keep = mask[t] != 0;
    int b = t >> 11, l = t & (NL - 1);
    out[attn_off() + (size_t)b * LP1 + l + 1] = keep ? 1.0f : 0.0f;
    if (t < NB) out[attn_off() + (size_t)t * LP1] = 1.0f;   // CLS keep
    int mr = mod[t] * 3 + role[t];
    int packed = t | (pos[t] << 14) | (mr << 27);           // 14+13+4 bits
    if (keep) {
        int idx = atomicAdd(&cnt[s], 1);
        if (idx < EXP_CAP) tokList[s * EXP_CAP + idx] = packed;
    } else {
        int ridx = atomicAdd(restCnt, 1);
        restList[ridx] = packed;
    }
}

// ---- kernel 2: tile descriptors (BM=128) + mod×role table ----
__global__ void k_tiles(const int* __restrict__ cnt, int* __restrict__ meta,
                        int4* __restrict__ tiles,
                        const float* __restrict__ me, const float* __restrict__ re,
                        float* __restrict__ mrT) {
    if (threadIdx.x == 0) {
        int idx = 0;
        for (int e = 0; e < NS; ++e) {
            int c = min(cnt[e], EXP_CAP);
            for (int r = 0; r < c; r += 128)
                tiles[idx++] = make_int4(e, r, min(128, c - r), 0);
        }
        meta[0] = idx;
    }
    for (int i = threadIdx.x; i < 12 * (NDM / 4); i += 256) {
        int mr = i / (NDM / 4); int o = (i % (NDM / 4)) * 4;
        int m = mr / 3, ro = mr % 3;
        float4 v = add4(ld4(me + (size_t)m * NDM + o), ld4(re + (size_t)ro * NDM + o));
        *(float4*)&mrT[(size_t)mr * NDM + o] = v;
    }
}

// ---- kernel 3: f32 -> bf16 for emb and W ----
__global__ void k_cvt(const float* __restrict__ emb, const float* __restrict__ W,
                      short* __restrict__ embBf, short* __restrict__ wBf) {
    size_t i = ((size_t)blockIdx.x * 256 + threadIdx.x) * 16;
    const float* src; short* dst;
    if (i < (size_t)EMB_ELEMS) { src = emb + i; dst = embBf + i; }
    else { src = W + (i - EMB_ELEMS); dst = wBf + (i - EMB_ELEMS); }
    float4 a = ld4(src), b = ld4(src + 4), c = ld4(src + 8), d = ld4(src + 12);
    *(bf16x8*)dst       = cvt8(a, b);
    *(bf16x8*)(dst + 8) = cvt8(c, d);
}

// ---- kernel 4: grouped GEMM, reg-staged (coalesced load -> swizzled ds_write) ----
__global__ __launch_bounds__(256, 3) void k_gemm(
    const short* __restrict__ embBf, const short* __restrict__ wBf,
    const int* __restrict__ tokList, const int4* __restrict__ tiles,
    const int* __restrict__ meta,
    const float* __restrict__ bp, const float* __restrict__ pe,
    const float* __restrict__ ie, const float* __restrict__ mrT,
    float* __restrict__ out) {
    if (blockIdx.x >= meta[0]) return;
    int4 td = tiles[blockIdx.x];
    const int e = td.x, rowBase = td.y, nRows = td.z;
    const int nBase = blockIdx.y * 128;

    __shared__ short SA[128 * 32];   // 8 KB, single buffer
    __shared__ short SB[128 * 32];   // 8 KB

    const int tid  = threadIdx.x;
    const int lane = tid & 63;
    const int w    = tid >> 6;
    const int wr   = w >> 1, wc = w & 1;    // 2x2 waves, 64x64 out each
    const int fr   = lane & 15, kg = lane >> 4;

    // staging geometry: thread covers rows (srow, srow+64), 16B chunk sch.
    // ds_write address carries the XOR swizzle chunk^((row>>1)&3); global loads
    // are plain coalesced; ds_read uses the same involution.
    const int srow = tid >> 2;              // 0..63
    const int sch  = tid & 3;
    const size_t eBase = (size_t)e * EXP_CAP + rowBase;
    int ar0 = (srow < nRows) ? srow : 0;
    int ar1 = (srow + 64 < nRows) ? srow + 64 : 0;
    int tok0 = tokList[eBase + ar0] & 16383;
    int tok1 = tokList[eBase + ar1] & 16383;
    const short* a0 = embBf + (size_t)tok0 * ND + sch * 8;
    const short* a1 = embBf + (size_t)tok1 * ND + sch * 8;
    const short* b0 = wBf + ((size_t)e * NDM + nBase + srow) * ND + sch * 8;
    const short* b1 = wBf + ((size_t)e * NDM + nBase + srow + 64) * ND + sch * 8;
    const int wo0 = srow * 32 + (sch ^ ((srow >> 1) & 3)) * 8;
    const int wo1 = wo0 + 64 * 32;          // (srow+64)>>1 == srow>>1 (mod 4)

    // epilogue col-invariants
    const float* bpE = bp + (size_t)e * NDM;
    const float* ieE = ie + (size_t)e * NDM;
    float eb[4]; int colv[4];
#pragma unroll
    for (int j = 0; j < 4; ++j) {
        colv[j] = nBase + wc * 64 + j * 16 + fr;
        eb[j] = bpE[colv[j]] + ieE[colv[j]];
    }

    f32x4 acc[4][4];
#pragma unroll
    for (int i = 0; i < 4; ++i)
#pragma unroll
        for (int j = 0; j < 4; ++j)
            acc[i][j] = (f32x4){0.f, 0.f, 0.f, 0.f};

    bf16x8 ra0 = *(const bf16x8*)a0;
    bf16x8 ra1 = *(const bf16x8*)a1;
    bf16x8 rb0 = *(const bf16x8*)b0;
    bf16x8 rb1 = *(const bf16x8*)b1;

    const int pc = kg ^ ((fr >> 1) & 3);    // swizzled physical chunk (lane-const)
    for (int ks = 0; ks < ND / 32; ++ks) {  // 16 K-steps
        __syncthreads();                    // previous step's reads complete
        *(bf16x8*)&SA[wo0] = ra0;           // compiler waits vmcnt for ra*/rb*
        *(bf16x8*)&SA[wo1] = ra1;
        *(bf16x8*)&SB[wo0] = rb0;
        *(bf16x8*)&SB[wo1] = rb1;
        __syncthreads();                    // writes visible to all waves
        if (ks < ND / 32 - 1) {             // issue next-step loads; retire under MFMA
            ra0 = *(const bf16x8*)(a0 + (ks + 1) * 32);
            ra1 = *(const bf16x8*)(a1 + (ks + 1) * 32);
            rb0 = *(const bf16x8*)(b0 + (ks + 1) * 32);
            rb1 = *(const bf16x8*)(b1 + (ks + 1) * 32);
        }
        bf16x8 af[4], bv[4];
#pragma unroll
        for (int i = 0; i < 4; ++i)
            af[i] = *(const bf16x8*)&SA[(wr * 64 + i * 16 + fr) * 32 + pc * 8];
#pragma unroll
        for (int j = 0; j < 4; ++j)
            bv[j] = *(const bf16x8*)&SB[(wc * 64 + j * 16 + fr) * 32 + pc * 8];
#pragma unroll
        for (int i = 0; i < 4; ++i)
#pragma unroll
            for (int j = 0; j < 4; ++j)
                acc[i][j] = __builtin_amdgcn_mfma_f32_16x16x32_bf16(af[i], bv[j], acc[i][j], 0, 0, 0);
    }

    // fused epilogue (r5-proven): full value write, no RMW
#pragma unroll
    for (int i = 0; i < 4; ++i) {
#pragma unroll
        for (int r = 0; r < 4; ++r) {
            int row = wr * 64 + i * 16 + kg * 4 + r;
            if (row < nRows) {
                int pk = tokList[eBase + row];
                int t = pk & 16383, p = (pk >> 14) & 8191, mr = (pk >> 27) & 15;
                const float* peR = pe + (size_t)p * NDM;
                const float* mrR = mrT + (size_t)mr * NDM;
                size_t orow = ((size_t)(t >> 11) * LP1 + (t & (NL - 1)) + 1) * NDM;
#pragma unroll
                for (int j = 0; j < 4; ++j)
                    out[orow + colv[j]] = acc[i][j][r] + eb[j] + peR[colv[j]] + mrR[colv[j]];
            }
        }
    }
}

// ---- kernel 5: rest rows (padded tokens) + CLS rows, compact grid-stride ----
__global__ void k_rest(const int* __restrict__ sid,
                       const int* __restrict__ restList, const int* __restrict__ meta,
                       const float* __restrict__ cls_c, const float* __restrict__ pos_e,
                       const float* __restrict__ id_e, const float* __restrict__ mrT,
                       float* __restrict__ out) {
    int total = meta[1] + NB;               // rest rows + CLS rows
    int half = threadIdx.x >> 7;            // 2 rows per 256-thread block
    int o = (threadIdx.x & 127) * 8;        // 128 threads x 8 floats = 1024
    for (int rI = blockIdx.x * 2 + half; rI < total; rI += gridDim.x * 2) {
        float4 v0, v1; size_t orow;
        if (rI < NB) {
            const float* ieC = id_e + (size_t)NS * NDM;
            v0 = add4(add4(ld4(cls_c + o), ld4(pos_e + o)), ld4(ieC + o));
            v1 = add4(add4(ld4(cls_c + o + 4), ld4(pos_e + o + 4)), ld4(ieC + o + 4));
            orow = (size_t)rI * LP1 * NDM;
        } else {
            int pk = restList[rI - NB];
            int t = pk & 16383, p = (pk >> 14) & 8191, mr = (pk >> 27) & 15;
            int s = sid[t];
            const float* peR = pos_e + (size_t)p * NDM;
            const float* ieR = id_e + (size_t)s * NDM;
            const float* mrR = mrT + (size_t)mr * NDM;
            v0 = add4(add4(ld4(peR + o), ld4(ieR + o)), ld4(mrR + o));
            v1 = add4(add4(ld4(peR + o + 4), ld4(ieR + o + 4)), ld4(mrR + o + 4));
            orow = ((size_t)(t >> 11) * LP1 + (t & (NL - 1)) + 1) * NDM;
        }
        *(float4*)&out[orow + o] = v0;
        *(float4*)&out[orow + o + 4] = v1;
    }
}

extern "C" void kernel_launch(void* const* d_in, const int* in_sizes, int n_in,
                              void* d_out, int out_size, void* d_ws, size_t ws_size,
                              hipStream_t stream) {
    const float* emb  = (const float*)d_in[0];
    const int* pos    = (const int*)d_in[1];
    const int* sid    = (const int*)d_in[2];
    const int* mod    = (const int*)d_in[3];
    const int* role   = (const int*)d_in[4];
    const int* mask   = (const int*)d_in[5];   // np.bool_ pushed as int32
    const float* Wp   = (const float*)d_in[6];
    const float* bp   = (const float*)d_in[7];
    const float* cls  = (const float*)d_in[8];
    const float* pe   = (const float*)d_in[9];
    const float* ie   = (const float*)d_in[10];
    const float* me   = (const float*)d_in[11];
    const float* re   = (const float*)d_in[12];
    float* out = (float*)d_out;

    int* ws        = (int*)d_ws;
    int* cnt       = ws;                          // [0..31]
    int* meta      = ws + 32;                     // [32]=tileCnt, [33]=restCnt
    int4* tiles    = (int4*)(ws + 128);           // 160 * int4
    int* tokList   = ws + 1024;                   // 32*1024
    int* restList  = ws + 33792;                  // 16384
    float* mrT     = (float*)(ws + 50176);        // 12*1024
    short* embBf   = (short*)((char*)d_ws + 262144);
    short* wBf     = (short*)((char*)d_ws + 262144 + (size_t)EMB_ELEMS * 2);
    // total ws: 262144 + 16.78MB + 33.55MB = 50.6 MB

    hipMemsetAsync(ws, 0, 64 * sizeof(int), stream);
    k_bucket<<<NTOK / 256, 256, 0, stream>>>(sid, mask, pos, mod, role,
                                             cnt, meta + 1, tokList, restList, out);
    k_tiles<<<1, 256, 0, stream>>>(cnt, meta, tiles, me, re, mrT);
    k_cvt<<<(EMB_ELEMS + W_ELEMS) / (256 * 16), 256, 0, stream>>>(emb, Wp, embBf, wBf);

    dim3 gg(MAXTILES, NDM / 128);
    k_gemm<<<gg, 256, 0, stream>>>(embBf, wBf, tokList, tiles, meta,
                                   bp, pe, ie, mrT, out);
    k_rest<<<512, 256, 0, stream>>>(sid, restList, meta, cls, pe, ie, mrT, out);
}